// Round 1
// 242.210 us; speedup vs baseline: 1.0593x; 1.0593x over previous
//
#include <hip/hip_runtime.h>
#include <hip/hip_bf16.h>
#include <stdint.h>

// ---------------------------------------------------------------------------
// SplitCausalSelfAttention on MI355X (gfx950), bf16 MFMA implementation.
// B=4, T=2048, C=1024, H=16, D=64.
// R12: qkv + proj rewritten on an 8-phase-style counted-vmcnt pipelined GEMM
//      core (T3+T4+T5 per learn_hip m196-m218): BM=128 x BN=256 x BK=64,
//      512 thr (8 waves, 2m x 4n), 2 phases per K-tile, one 24KB k-slab
//      group staged per phase via global_load_lds, vmcnt(6) counted waits
//      (never 0 in steady state), s_setprio(1) around the 16-MFMA cluster.
//      qkv = ONE concatenated GEMM [8192x3072x1024], grid 768 = 3 x 256 CUs
//      (even rounds); per-block epilogue dispatches Q(scaled)/K/V^T with the
//      V blocks using swapped MFMA operands (lanes hold contiguous t).
//      proj: same core, grid 256 = exactly one round, direct f32x4+bias.
//      attn + cast unchanged from R11.
// ---------------------------------------------------------------------------

typedef unsigned short u16;
typedef __attribute__((ext_vector_type(8))) __bf16 bf16x8;  // 4 VGPRs (A/B frag, K=32)
typedef __attribute__((ext_vector_type(4))) float  f32x4;   // C/D frag
typedef __attribute__((ext_vector_type(4))) unsigned short u16x4;
typedef __attribute__((ext_vector_type(8))) unsigned short u16x8;
typedef __attribute__((ext_vector_type(4))) short s16x4;    // 2 VGPRs (A/B frag, K=16)

#define B_  4
#define T_  2048
#define C_  1024
#define H_  16
#define D_  64
#define BT_ (B_ * T_)
#define NT_ 16        // K-tiles of 64 over K=1024

// scale = 1/sqrt(D) folded with log2(e) so softmax uses exp2
#define Q_SCALE 0.1803368801111204f

__device__ __forceinline__ u16 f32_to_bf16(float f) {
    unsigned int u = __float_as_uint(f);
    unsigned int r = (u + 0x7FFFu + ((u >> 16) & 1u)) >> 16;
    return (u16)r;
}

__device__ __forceinline__ unsigned int pk_bf16(float a, float b) {
    float2 f2; f2.x = a; f2.y = b;
    __hip_bfloat162 h = __float22bfloat162_rn(f2);
    return *(unsigned int*)&h;
}

__device__ __forceinline__ void async16(const void* g, void* lds) {
    __builtin_amdgcn_global_load_lds(
        (const __attribute__((address_space(1))) void*)g,
        (__attribute__((address_space(3))) void*)lds, 16, 0, 0);
}

// ---------------------------------------------------------------------------
// single cast kernel: X (8192 blocks) + 4 weights (1024 blocks each)
// ---------------------------------------------------------------------------
__global__ void cast_all_kernel(const float* __restrict__ X,
                                const float* __restrict__ w0, const float* __restrict__ w1,
                                const float* __restrict__ w2, const float* __restrict__ w3,
                                u16* __restrict__ xo,
                                u16* __restrict__ o0, u16* __restrict__ o1,
                                u16* __restrict__ o2, u16* __restrict__ o3) {
    int id = blockIdx.x;
    const float* in; u16* out; int i;
    if (id < 8192) {
        in = X; out = xo; i = id * 256 + threadIdx.x;
    } else {
        int k = (id - 8192) >> 10;
        in  = (k == 0) ? w0 : (k == 1) ? w1 : (k == 2) ? w2 : w3;
        out = (k == 0) ? o0 : (k == 1) ? o1 : (k == 2) ? o2 : o3;
        i = ((id - 8192) & 1023) * 256 + threadIdx.x;
    }
    float4 v = ((const float4*)in)[i];
    u16x4 o;
    o[0] = f32_to_bf16(v.x); o[1] = f32_to_bf16(v.y);
    o[2] = f32_to_bf16(v.z); o[3] = f32_to_bf16(v.w);
    ((u16x4*)out)[i] = o;
}

// ---------------------------------------------------------------------------
// Pipelined GEMM core (counted-vmcnt, 2 phases per K-tile).
// Arow: m-operand base row (BM=128 rows of [.., C_]); Brow: n-operand base
// row (BN=256 rows of [.., C_]).  acc[i][j]:
//   SWAP=false: mfma(Wfrag, Xfrag) -> D row = n(ch) via (quad,reg), col = m(t) via l15
//   SWAP=true : mfma(Xfrag, Wfrag) -> D row = m(t),  col = n(ch)
// LDS per buffer 48KB: X [2ks][128][32] @0, W [2ks][256][32] @16384.
// Staging swizzle: chunk c -> row=c>>2, slot=c&3 holds global k-group
// (slot-(row>>1))&3; reads use slot=((row>>1)+quad)&3  (R11's measured
// 0-bank-conflict pattern, pre-swizzled global source for global_load_lds).
// ---------------------------------------------------------------------------
template<bool SWAP>
__device__ __forceinline__ void gemm8_core(const u16* __restrict__ Arow,
                                           const u16* __restrict__ Brow,
                                           char* lds, f32x4 (&acc)[4][4])
{
    int tid  = threadIdx.x;
    int lane = tid & 63, w = tid >> 6;
    int quad = lane >> 4, l15 = lane & 15;
    int wm = w >> 2, wn = w & 3;

    // staging source (per-thread, pre-swizzled) and wave-uniform dest
    int r  = tid >> 2, s4 = tid & 3;
    int kg = ((s4 - (r >> 1)) & 3) * 8;
    const u16* xsrc  = Arow + (size_t)r * C_ + kg;
    const u16* wsrc0 = Brow + (size_t)r * C_ + kg;
    const u16* wsrc1 = Brow + (size_t)(128 + r) * C_ + kg;
    int wu = w << 10;                      // wave base (HW adds lane*16)

    // loop-invariant LDS read byte offsets
    int xoff[4], woff[4];
#pragma unroll
    for (int i = 0; i < 4; ++i) {
        int rx = wm * 64 + i * 16 + l15;
        xoff[i] = rx * 64 + (((rx >> 1) + quad) & 3) * 16;
        int rw = wn * 64 + i * 16 + l15;
        woff[i] = 16384 + rw * 64 + (((rw >> 1) + quad) & 3) * 16;
    }

    // one group = one k-slab of the tile = {X 8KB, W 16KB} = 3 async16/thread
    auto issue_group = [&](int g) {
        int db = (g >> 1) & 1, ks = g & 1;
        int koff = (g >> 1) * 64 + ks * 32;          // u16 elements
        char* ldb = lds + db * 49152;
        async16(xsrc  + koff, ldb + ks * 8192 + wu);
        async16(wsrc0 + koff, ldb + 16384 + ks * 16384 + wu);
        async16(wsrc1 + koff, ldb + 16384 + ks * 16384 + 8192 + wu);
    };

    // prologue: tile0 both slabs + tile1 ks0; gate tile0.ks0 (vmcnt 6 = 2 grp)
    issue_group(0); issue_group(1); issue_group(2);
    asm volatile("s_waitcnt vmcnt(6)" ::: "memory");
    __builtin_amdgcn_s_barrier();
    asm volatile("" ::: "memory");

    for (int t = 0; t < NT_; ++t) {
        char* cb = lds + (t & 1) * 49152;
#pragma unroll
        for (int p = 0; p < 2; ++p) {
            // 8 x ds_read_b128 (overlaps staging + barrier wait)
            bf16x8 xf[4], wf[4];
            const char* xb = cb + p * 8192;
            const char* wb = cb + p * 16384;
#pragma unroll
            for (int i = 0; i < 4; ++i) xf[i] = *(const bf16x8*)(xb + xoff[i]);
#pragma unroll
            for (int j = 0; j < 4; ++j) wf[j] = *(const bf16x8*)(wb + woff[j]);

            // stage stream: t.p0 -> (t+1)ks1 (other buf); t.p1 -> (t+2)ks0
            // (same buf ks0: last read at t.p0, issue sits after its barrier)
            int g = 2 * t + 3 + p;
            if (g < 2 * NT_) issue_group(g);

            // counted residency gate for NEXT phase's group (never 0 until tail)
            if (t < NT_ - 2) {
                asm volatile("s_waitcnt vmcnt(6)" ::: "memory");
            } else if (t == NT_ - 2) {
                if (p == 0) asm volatile("s_waitcnt vmcnt(6)" ::: "memory");
                else        asm volatile("s_waitcnt vmcnt(3)" ::: "memory");
            } else {
                if (p == 0) asm volatile("s_waitcnt vmcnt(0)" ::: "memory");
            }
            asm volatile("" ::: "memory");
            __builtin_amdgcn_s_barrier();          // A: residency + phase-lock
            asm volatile("" ::: "memory");

            __builtin_amdgcn_s_setprio(1);
#pragma unroll
            for (int i = 0; i < 4; ++i)
#pragma unroll
                for (int j = 0; j < 4; ++j) {
                    if (SWAP)
                        acc[i][j] = __builtin_amdgcn_mfma_f32_16x16x32_bf16(xf[i], wf[j], acc[i][j], 0, 0, 0);
                    else
                        acc[i][j] = __builtin_amdgcn_mfma_f32_16x16x32_bf16(wf[j], xf[i], acc[i][j], 0, 0, 0);
                }
            __builtin_amdgcn_s_setprio(0);
            asm volatile("" ::: "memory");
            __builtin_amdgcn_s_barrier();          // B: WAR gate for staging
            asm volatile("" ::: "memory");
        }
    }
}

// ---------------------------------------------------------------------------
// Fused QKV: C[8192,3072] = X . [Wq;Wk;Wv]^T as one GEMM.
// Grid 768 = 8 XCD x 96 (bm-contiguous per XCD); bm=wg/12 (128-row X tile),
// bn=wg%12 (256 cols: bn>>2 = matrix, (bn&3)*256 = channel base).
// ---------------------------------------------------------------------------
__global__ __launch_bounds__(512, 2) void qkv_gemm8(
    const u16* __restrict__ Xb,
    const u16* __restrict__ Wqb, const u16* __restrict__ Wkb, const u16* __restrict__ Wvb,
    u16* __restrict__ Qb, u16* __restrict__ Kb, u16* __restrict__ Vtb)
{
    __shared__ __attribute__((aligned(128))) char LDSRAW[98304];

    int id = blockIdx.x;
    int wg = (id & 7) * 96 + (id >> 3);      // bijective XCD swizzle (768=8*96)
    int bm = wg / 12, bn = wg % 12;
    int m0 = bm * 128;
    int nmat = bn >> 2;
    int chb  = (bn & 3) * 256;

    const u16* Wsel = (nmat == 0) ? Wqb : (nmat == 1) ? Wkb : Wvb;
    const u16* Arow = Xb   + (size_t)m0  * C_;
    const u16* Brow = Wsel + (size_t)chb * C_;

    f32x4 acc[4][4];
    const f32x4 z4 = {0.f, 0.f, 0.f, 0.f};
#pragma unroll
    for (int i = 0; i < 4; ++i)
#pragma unroll
        for (int j = 0; j < 4; ++j) acc[i][j] = z4;

    int tid = threadIdx.x, lane = tid & 63, w = tid >> 6;
    int quad = lane >> 4, l15 = lane & 15;
    int wm = w >> 2, wn = w & 3;

    if (nmat < 2) {
        gemm8_core<false>(Arow, Brow, LDSRAW, acc);
        // Q/K epilogue: lane holds 4 consecutive ch at fixed t
        u16* OUT = nmat ? Kb : Qb;
        float scale = nmat ? 1.0f : Q_SCALE;
#pragma unroll
        for (int i = 0; i < 4; ++i) {
            size_t trow = (size_t)(m0 + wm * 64 + i * 16 + l15) * C_;
#pragma unroll
            for (int j = 0; j < 4; ++j) {
                int ch = chb + wn * 64 + j * 16 + quad * 4;
                u16x4 v;
#pragma unroll
                for (int rr = 0; rr < 4; ++rr) v[rr] = f32_to_bf16(acc[i][j][rr] * scale);
                *(u16x4*)&OUT[trow + ch] = v;
            }
        }
    } else {
        gemm8_core<true>(Arow, Brow, LDSRAW, acc);
        // V epilogue: lane holds 4 consecutive t at fixed ch -> [B,H,D,T]
#pragma unroll
        for (int i = 0; i < 4; ++i) {
            int t0 = m0 + wm * 64 + i * 16 + quad * 4;
            int bb_ = t0 >> 11, tloc = t0 & (T_ - 1);
#pragma unroll
            for (int j = 0; j < 4; ++j) {
                int ch = chb + wn * 64 + j * 16 + l15;
                int h = ch >> 6, d = ch & 63;
                u16x4 v;
#pragma unroll
                for (int rr = 0; rr < 4; ++rr) v[rr] = f32_to_bf16(acc[i][j][rr]);
                *(u16x4*)&Vtb[(size_t)((bb_ * H_ + h) * D_ + d) * T_ + tloc] = v;
            }
        }
    }
}

// ---------------------------------------------------------------------------
// Flash attention (causal), S^T/O^T, max-free softmax, register-resident P.
// (unchanged from R11)
// ---------------------------------------------------------------------------
__global__ __launch_bounds__(256, 4) void attn_kernel(
    const u16* __restrict__ Qb, const u16* __restrict__ Kb,
    const u16* __restrict__ Vtb, u16* __restrict__ Yb)
{
    __shared__ u16 SMA[16384];       // Ks0|Ks1|Vs0|Vs1 (4x8KB), reused by epilogue
    u16* Ks0 = SMA;
    u16* Ks1 = SMA + 4096;
    u16* Vs0 = SMA + 8192;
    u16* Vs1 = SMA + 12288;

    int id = blockIdx.x;
    int bh = id & 63;
    int jj = id >> 6;                // 0..15

    int tid = threadIdx.x, lane = tid & 63, w = tid >> 6;
    int quad = lane >> 4, l15 = lane & 15;
    int b = bh >> 4, h = bh & 15;

    // loop-invariant LDS byte offsets (K: 8 x b128, V: 16 x b64)
    int koff0[4], koff1[4], voff[4][4];
#pragma unroll
    for (int sblk = 0; sblk < 4; ++sblk) {
        int sr = sblk * 16 + l15;
        koff0[sblk] = (sr * 64 + ((quad + sr) & 7) * 8) * 2;
        koff1[sblk] = (sr * 64 + ((4 + quad + sr) & 7) * 8) * 2;
    }
#pragma unroll
    for (int n = 0; n < 4; ++n)
#pragma unroll
        for (int sblk = 0; sblk < 4; ++sblk) {
            int dr = n * 16 + l15;
            voff[n][sblk] = (dr * 64 + ((sblk * 2 + (quad >> 1) + dr) & 7) * 8 + (quad & 1) * 4) * 2;
        }

    // staging chunk assignment (512 chunks of 16B per 8KB tile, 2 passes)
    int cA = tid, cB = tid + 256;
    int sA = cA >> 3, sB = cB >> 3;
    int offA = (((cA & 7) - sA) & 7) * 8;
    int offB = (((cB & 7) - sB) & 7) * 8;
    const u16* Kbase = Kb + (size_t)(b * T_) * C_ + h * 64;
    const u16* Vbase = Vtb + (size_t)bh * D_ * T_;
    int ldsb0 = (w * 64) * 16, ldsb1 = (256 + w * 64) * 16;

    const s16x4 ones = { (short)0x3F80, (short)0x3F80, (short)0x3F80, (short)0x3F80 };
    const f32x4 z4 = {0.f, 0.f, 0.f, 0.f};

    int qts[2] = { jj, 31 - jj };

    for (int pass = 0; pass < 2; ++pass) {
        int qt = qts[pass];
        int qbase = qt * 64;

        if (pass) __syncthreads();   // prior epilogue LDS reads done

        // Q B-frags from [BT,C]: wave w owns t = qbase + w*16 + l15
        bf16x8 qf0, qf1;
        {
            const u16* q0 = Qb + ((size_t)(b * T_ + qbase + w * 16 + l15)) * C_ + h * 64;
            qf0 = *(const bf16x8*)(q0 + quad * 8);
            qf1 = *(const bf16x8*)(q0 + 32 + quad * 8);
        }

        f32x4 o_acc[4];              // O^T: col t (l15), rows d=n*16+quad*4+r
        f32x4 l_acc = z4;            // all 4 regs identical = sum_s P[s,t]
#pragma unroll
        for (int n = 0; n < 4; ++n) o_acc[n] = z4;

        const int nst = qt + 1;      // number of 64-row K-tiles

        const u16* kgpA = Kbase + (size_t)sA * C_ + offA;
        const u16* kgpB = Kbase + (size_t)sB * C_ + offB;
        const u16* vgpA = Vbase + sA * T_ + offA;
        const u16* vgpB = Vbase + sB * T_ + offB;

        // prologue: stage tile 0 into buffer 0
        async16(kgpA, (char*)Ks0 + ldsb0);
        async16(kgpB, (char*)Ks0 + ldsb1);
        async16(vgpA, (char*)Vs0 + ldsb0);
        async16(vgpB, (char*)Vs0 + ldsb1);
        kgpA += 64 * C_; kgpB += 64 * C_; vgpA += 64; vgpB += 64;

        auto tile_body = [&](int st, const u16* K_, const u16* V_, char* Kpf, char* Vpf) {
            __syncthreads();   // tile st resident; prev reads done
            if (st + 1 < nst) {
                async16(kgpA, Kpf + ldsb0);
                async16(kgpB, Kpf + ldsb1);
                async16(vgpA, Vpf + ldsb0);
                async16(vgpB, Vpf + ldsb1);
            }
            kgpA += 64 * C_; kgpB += 64 * C_; vgpA += 64; vgpB += 64;

            // S^T = K Q^T : per wave 64(s) x 16(t)
            f32x4 sv[4];
#pragma unroll
            for (int sblk = 0; sblk < 4; ++sblk) {
                bf16x8 k0 = *(const bf16x8*)((const char*)K_ + koff0[sblk]);
                bf16x8 k1 = *(const bf16x8*)((const char*)K_ + koff1[sblk]);
                f32x4 t0 = __builtin_amdgcn_mfma_f32_16x16x32_bf16(k0, qf0, z4, 0, 0, 0);
                sv[sblk] = __builtin_amdgcn_mfma_f32_16x16x32_bf16(k1, qf1, t0, 0, 0, 0);
            }

            if (st == qt) {   // diagonal tile: causal mask (s > t), tile-local
                int tl = w * 16 + l15;
#pragma unroll
                for (int sblk = 0; sblk < 4; ++sblk)
#pragma unroll
                    for (int r = 0; r < 4; ++r)
                        if (sblk * 16 + quad * 4 + r > tl) sv[sblk][r] = -1e30f;
            }

            // max-free softmax: raw v_exp_f32, P packed to regs; l via ones-MFMA
            s16x4 pfrag[4];
#pragma unroll
            for (int sblk = 0; sblk < 4; ++sblk) {
#pragma unroll
                for (int r = 0; r < 4; ++r)
                    sv[sblk][r] = __builtin_amdgcn_exp2f(sv[sblk][r]);
                uint2 pk;
                pk.x = pk_bf16(sv[sblk][0], sv[sblk][1]);
                pk.y = pk_bf16(sv[sblk][2], sv[sblk][3]);
                pfrag[sblk] = *(s16x4*)&pk;
                l_acc = __builtin_amdgcn_mfma_f32_16x16x16bf16_1k(ones, pfrag[sblk], l_acc, 0, 0, 0);
            }

            // O^T += V^T P via mfma 16x16x16: A = V^T (LDS b64), B = pfrag
#pragma unroll
            for (int n = 0; n < 4; ++n)
#pragma unroll
                for (int sblk = 0; sblk < 4; ++sblk) {
                    s16x4 va = *(const s16x4*)((const char*)V_ + voff[n][sblk]);
                    o_acc[n] = __builtin_amdgcn_mfma_f32_16x16x16bf16_1k(va, pfrag[sblk], o_acc[n], 0, 0, 0);
                }
        };

        for (int st = 0; st < nst; st += 2) {
            tile_body(st, Ks0, Vs0, (char*)Ks1, (char*)Vs1);
            if (st + 1 < nst)
                tile_body(st + 1, Ks1, Vs1, (char*)Ks0, (char*)Vs0);
        }

        // epilogue: LDS transpose (wave-private, stride 72) -> coalesced stores
        __syncthreads();             // all waves done reading K/V LDS
        u16* PW = SMA + w * 1152;    // 16 rows x 72 elems per wave
        {
            float inv = 1.0f / l_acc[0];   // all regs equal (ones-MFMA)
#pragma unroll
            for (int n = 0; n < 4; ++n) {
                uint2 pk;
                pk.x = pk_bf16(o_acc[n][0] * inv, o_acc[n][1] * inv);
                pk.y = pk_bf16(o_acc[n][2] * inv, o_acc[n][3] * inv);
                *(u16x4*)&PW[l15 * 72 + n * 16 + quad * 4] = *(u16x4*)&pk;
            }
        }
        asm volatile("s_waitcnt lgkmcnt(0)" ::: "memory");   // wave-private
#pragma unroll
        for (int st = 0; st < 2; ++st) {
            int tr = st * 8 + (lane >> 3);      // 0..15
            int d8 = (lane & 7) * 8;
            u16x8 v = *(u16x8*)&PW[tr * 72 + d8];
            *(u16x8*)&Yb[(size_t)(b * T_ + qbase + w * 16 + tr) * C_ + h * 64 + d8] = v;
        }
    }
}

// ---------------------------------------------------------------------------
// Output projection on the pipelined core.  out[t,ch] = Y.Wo^T + bo.
// Grid 256 = 8 XCD x 32 = exactly one residency round (1 block/CU).
// Lane holds 4 consecutive ch at fixed t -> direct f32x4 + bias stores.
// ---------------------------------------------------------------------------
__global__ __launch_bounds__(512, 2) void proj_gemm8(
    const u16* __restrict__ Yb, const u16* __restrict__ Wob,
    const float* __restrict__ bo, float* __restrict__ out)
{
    __shared__ __attribute__((aligned(128))) char LDSRAW[98304];

    int id = blockIdx.x;
    int wg = (id & 7) * 32 + (id >> 3);      // bijective XCD swizzle (256=8*32)
    int bm = wg >> 2, bn = wg & 3;
    int m0 = bm * 128, n0 = bn * 256;

    f32x4 acc[4][4];
    const f32x4 z4 = {0.f, 0.f, 0.f, 0.f};
#pragma unroll
    for (int i = 0; i < 4; ++i)
#pragma unroll
        for (int j = 0; j < 4; ++j) acc[i][j] = z4;

    gemm8_core<false>(Yb + (size_t)m0 * C_, Wob + (size_t)n0 * C_, LDSRAW, acc);

    int tid = threadIdx.x, lane = tid & 63, w = tid >> 6;
    int quad = lane >> 4, l15 = lane & 15;
    int wm = w >> 2, wn = w & 3;

#pragma unroll
    for (int j = 0; j < 4; ++j) {
        int ch = n0 + wn * 64 + j * 16 + quad * 4;
        f32x4 bv = *(const f32x4*)&bo[ch];
#pragma unroll
        for (int i = 0; i < 4; ++i) {
            int t = m0 + wm * 64 + i * 16 + l15;
            f32x4 v = acc[i][j] + bv;
            *(f32x4*)&out[(size_t)t * C_ + ch] = v;
        }
    }
}

// ---------------------------------------------------------------------------
// launch
// ---------------------------------------------------------------------------
extern "C" void kernel_launch(void* const* d_in, const int* in_sizes, int n_in,
                              void* d_out, int out_size, void* d_ws, size_t ws_size,
                              hipStream_t stream) {
    const float* X  = (const float*)d_in[0];
    const float* Wq = (const float*)d_in[1];
    const float* Wk = (const float*)d_in[2];
    const float* Wv = (const float*)d_in[3];
    const float* Wo = (const float*)d_in[4];
    const float* bo = (const float*)d_in[5];

    char* ws = (char*)d_ws;
    u16* Xb  = (u16*)(ws);                       // 16 MB  [BT, C] bf16
    u16* Wqb = (u16*)(ws + (16u << 20));         //  2 MB
    u16* Wkb = (u16*)(ws + (18u << 20));         //  2 MB
    u16* Wvb = (u16*)(ws + (20u << 20));         //  2 MB
    u16* Wob = (u16*)(ws + (22u << 20));         //  2 MB
    u16* Qb  = (u16*)(ws + (24u << 20));         // 16 MB  [BT, C] (pre-scaled)
    u16* Kb  = (u16*)(ws + (40u << 20));         // 16 MB  [BT, C]
    u16* Vtb = (u16*)(ws + (56u << 20));         // 16 MB  [B,H,D,T]
    u16* Yb  = (u16*)(ws + (72u << 20));         // 16 MB  [BT, C]

    cast_all_kernel<<<dim3(8192 + 4 * 1024), 256, 0, stream>>>(
        X, Wq, Wk, Wv, Wo, Xb, Wqb, Wkb, Wvb, Wob);

    qkv_gemm8<<<dim3(768), 512, 0, stream>>>(Xb, Wqb, Wkb, Wvb, Qb, Kb, Vtb);
    attn_kernel<<<dim3(1024), 256, 0, stream>>>(Qb, Kb, Vtb, Yb);
    proj_gemm8<<<dim3(256), 512, 0, stream>>>(Yb, Wob, bo, (float*)d_out);
}

// Round 2
// 241.204 us; speedup vs baseline: 1.0637x; 1.0042x over previous
//
#include <hip/hip_runtime.h>
#include <hip/hip_bf16.h>
#include <stdint.h>

// ---------------------------------------------------------------------------
// SplitCausalSelfAttention on MI355X (gfx950), bf16 MFMA implementation.
// B=4, T=2048, C=1024, H=16, D=64.
// R13: qkv moved to the m201-style 256x256 4-phase-per-K-tile schedule:
//      512 thr (8 waves 2Mx4N), LDS 128KB = 2 dbuf x 4 units (A-lo/A-hi/
//      B-lo/B-hi, 16KB each), interleaved wave mapping so phase (mh,nh)
//      reads exactly units {mh, 2+nh}; 1 unit staged per phase into the
//      other dbuf (order u0,u2,u3,u1), counted vmcnt(4) gates at phases
//      0/1/3 (none at 2; never 0 until last tile), setprio(1) around each
//      16-MFMA cluster, xf/wf register reuse across phases.  Grid 384 =
//      32m x 12n (8 XCD x 48).  proj/attn/cast unchanged from R12.
// ---------------------------------------------------------------------------

typedef unsigned short u16;
typedef __attribute__((ext_vector_type(8))) __bf16 bf16x8;  // 4 VGPRs (A/B frag, K=32)
typedef __attribute__((ext_vector_type(4))) float  f32x4;   // C/D frag
typedef __attribute__((ext_vector_type(4))) unsigned short u16x4;
typedef __attribute__((ext_vector_type(8))) unsigned short u16x8;
typedef __attribute__((ext_vector_type(4))) short s16x4;    // 2 VGPRs (A/B frag, K=16)

#define B_  4
#define T_  2048
#define C_  1024
#define H_  16
#define D_  64
#define BT_ (B_ * T_)
#define NT_ 16        // K-tiles of 64 over K=1024

// scale = 1/sqrt(D) folded with log2(e) so softmax uses exp2
#define Q_SCALE 0.1803368801111204f

__device__ __forceinline__ u16 f32_to_bf16(float f) {
    unsigned int u = __float_as_uint(f);
    unsigned int r = (u + 0x7FFFu + ((u >> 16) & 1u)) >> 16;
    return (u16)r;
}

__device__ __forceinline__ unsigned int pk_bf16(float a, float b) {
    float2 f2; f2.x = a; f2.y = b;
    __hip_bfloat162 h = __float22bfloat162_rn(f2);
    return *(unsigned int*)&h;
}

__device__ __forceinline__ void async16(const void* g, void* lds) {
    __builtin_amdgcn_global_load_lds(
        (const __attribute__((address_space(1))) void*)g,
        (__attribute__((address_space(3))) void*)lds, 16, 0, 0);
}

// ---------------------------------------------------------------------------
// single cast kernel: X (8192 blocks) + 4 weights (1024 blocks each)
// ---------------------------------------------------------------------------
__global__ void cast_all_kernel(const float* __restrict__ X,
                                const float* __restrict__ w0, const float* __restrict__ w1,
                                const float* __restrict__ w2, const float* __restrict__ w3,
                                u16* __restrict__ xo,
                                u16* __restrict__ o0, u16* __restrict__ o1,
                                u16* __restrict__ o2, u16* __restrict__ o3) {
    int id = blockIdx.x;
    const float* in; u16* out; int i;
    if (id < 8192) {
        in = X; out = xo; i = id * 256 + threadIdx.x;
    } else {
        int k = (id - 8192) >> 10;
        in  = (k == 0) ? w0 : (k == 1) ? w1 : (k == 2) ? w2 : w3;
        out = (k == 0) ? o0 : (k == 1) ? o1 : (k == 2) ? o2 : o3;
        i = ((id - 8192) & 1023) * 256 + threadIdx.x;
    }
    float4 v = ((const float4*)in)[i];
    u16x4 o;
    o[0] = f32_to_bf16(v.x); o[1] = f32_to_bf16(v.y);
    o[2] = f32_to_bf16(v.z); o[3] = f32_to_bf16(v.w);
    ((u16x4*)out)[i] = o;
}

// ---------------------------------------------------------------------------
// qkv 256x256 4-phase core.
// LDS: dbuf d at d*65536; unit u at u*16384 (u0=A rows 0-127, u1=A 128-255,
// u2=B rows 0-127, u3=B 128-255).  Within a unit: row r (0..127), 8 slots of
// 16B; slot holds k-group (slot - r) & 7 (k-rotation swizzle, 2-way free).
// Wave mapping (interleaved): wave w: wm=w>>2, wn=w&3.
//   m-frag mi: rows (mi>>2)*128 + wm*64 + (mi&3)*16 + l15  (unit = mi>>2)
//   n-frag nj: cols (nj>>1)*128 + wn*32 + (nj&1)*16 + l15  (unit = 2+(nj>>1))
// Phase (mh,nh) = one C-quadrant x K=64 = 16 MFMA; reads units {mh, 2+nh};
// xf read at nh==0 phases, wf at mh==0 phases (reg reuse).
// Issue (into other dbuf, order u0,u2,u3,u1); gates vmcnt(4) at p0/p1/p3.
// ---------------------------------------------------------------------------
#define QPHASE(CB, MH, NH, DOISSUE, G, GATE)                                      \
  {                                                                               \
    if ((NH) == 0) {                                                              \
      _Pragma("unroll")                                                           \
      for (int f = 0; f < 4; ++f) {                                               \
        _Pragma("unroll")                                                         \
        for (int ks = 0; ks < 2; ++ks)                                            \
          xf[f][ks] = *(const bf16x8*)((CB) + (MH) * 16384 + axoff[f][ks]);       \
      }                                                                           \
    }                                                                             \
    if ((MH) == 0) {                                                              \
      _Pragma("unroll")                                                           \
      for (int e = 0; e < 2; ++e) {                                               \
        _Pragma("unroll")                                                         \
        for (int ks = 0; ks < 2; ++ks)                                            \
          wf[NH][e][ks] = *(const bf16x8*)((CB) + (NH) * 16384 + bwoff[e][ks]);   \
      }                                                                           \
    }                                                                             \
    if (DOISSUE) issue_unit(G);                                                   \
    if ((GATE) == 4)      asm volatile("s_waitcnt vmcnt(4)" ::: "memory");        \
    else if ((GATE) == 2) asm volatile("s_waitcnt vmcnt(2)" ::: "memory");        \
    else if ((GATE) == 0) asm volatile("s_waitcnt vmcnt(0)" ::: "memory");        \
    __builtin_amdgcn_s_barrier();                                                 \
    asm volatile("" ::: "memory");                                                \
    __builtin_amdgcn_s_setprio(1);                                                \
    _Pragma("unroll")                                                             \
    for (int f = 0; f < 4; ++f) {                                                 \
      _Pragma("unroll")                                                           \
      for (int e = 0; e < 2; ++e) {                                               \
        f32x4 a_ = acc[(MH) * 4 + f][(NH) * 2 + e];                               \
        if (SWAPV) {                                                              \
          a_ = __builtin_amdgcn_mfma_f32_16x16x32_bf16(xf[f][0], wf[NH][e][0], a_, 0, 0, 0); \
          a_ = __builtin_amdgcn_mfma_f32_16x16x32_bf16(xf[f][1], wf[NH][e][1], a_, 0, 0, 0); \
        } else {                                                                  \
          a_ = __builtin_amdgcn_mfma_f32_16x16x32_bf16(wf[NH][e][0], xf[f][0], a_, 0, 0, 0); \
          a_ = __builtin_amdgcn_mfma_f32_16x16x32_bf16(wf[NH][e][1], xf[f][1], a_, 0, 0, 0); \
        }                                                                         \
        acc[(MH) * 4 + f][(NH) * 2 + e] = a_;                                     \
      }                                                                           \
    }                                                                             \
    __builtin_amdgcn_s_setprio(0);                                                \
    asm volatile("" ::: "memory");                                                \
    __builtin_amdgcn_s_barrier();                                                 \
    asm volatile("" ::: "memory");                                                \
  }

template<bool SWAPV>
__device__ __forceinline__ void qkv256_core(const u16* __restrict__ Arow,
                                            const u16* __restrict__ Brow,
                                            char* lds, f32x4 (&acc)[8][4])
{
    int tid  = threadIdx.x;
    int lane = tid & 63, w = tid >> 6;
    int quad = lane >> 4, l15 = lane & 15;
    int wm = w >> 2, wn = w & 3;

    // staging: per unit, 2 loads/thread; linear LDS dest, pre-swizzled src.
    // li = L*512 + tid; row = li>>3 (L*64 + tid>>3); slot = tid&7;
    // global k-group = (slot - row) & 7 (row mod 8 == (tid>>3) & 7).
    int gc = (((tid & 7) - (tid >> 3)) & 7) * 8;
    const u16* xsrc0 = Arow + (size_t)(tid >> 3) * C_ + gc;
    const u16* xsrc1 = xsrc0 + (size_t)64 * C_;
    const u16* wsrc0 = Brow + (size_t)(tid >> 3) * C_ + gc;
    const u16* wsrc1 = wsrc0 + (size_t)64 * C_;

    auto issue_unit = [&](int g) {
        int u = g & 3, kt = g >> 2;
        char* d = lds + ((kt & 1) << 16) + (u << 14) + (w << 10);
        size_t off = (size_t)(u & 1) * (128 * C_) + (size_t)kt * 64;
        const u16* s0 = (u < 2) ? xsrc0 : wsrc0;
        const u16* s1 = (u < 2) ? xsrc1 : wsrc1;
        async16(s0 + off, d);
        async16(s1 + off, d + 8192);
    };

    // loop-invariant LDS read byte offsets (within unit; unit base added in macro)
    int axoff[4][2], bwoff[2][2];
#pragma unroll
    for (int f = 0; f < 4; ++f) {
        int r = wm * 64 + f * 16 + l15;
#pragma unroll
        for (int ks = 0; ks < 2; ++ks)
            axoff[f][ks] = r * 128 + (((ks * 4 + quad + r) & 7) << 4);
    }
#pragma unroll
    for (int e = 0; e < 2; ++e) {
        int r = wn * 32 + e * 16 + l15;
#pragma unroll
        for (int ks = 0; ks < 2; ++ks)
            bwoff[e][ks] = 32768 + r * 128 + (((ks * 4 + quad + r) & 7) << 4);
    }

    bf16x8 xf[4][2];       // A-frags for current mh (read at nh==0 phases)
    bf16x8 wf[2][2][2];    // B-frags for both nh (read at mh==0 phases)

    // prologue: tile0 units in first-need order; gate u0,u2 (leaves u3,u1 in flight)
    issue_unit(0); issue_unit(2); issue_unit(3); issue_unit(1);
    asm volatile("s_waitcnt vmcnt(4)" ::: "memory");
    __builtin_amdgcn_s_barrier();
    asm volatile("" ::: "memory");

    for (int t = 0; t < NT_ - 1; ++t) {
        char* cb = lds + ((t & 1) << 16);
        int g4 = (t + 1) << 2;
        QPHASE(cb, 0, 0, 1, g4 + 0, 4);    // reads u0,u2; issue next.u0
        QPHASE(cb, 0, 1, 1, g4 + 2, 4);    // reads u3;    issue next.u2
        QPHASE(cb, 1, 0, 1, g4 + 3, -1);   // reads u1;    issue next.u3
        QPHASE(cb, 1, 1, 1, g4 + 1, 4);    // pure reg;    issue next.u1
    }
    {   // peeled last tile (NT_-1 = 15, odd -> dbuf 1): tail drain 2 -> 0
        char* cb = lds + (((NT_ - 1) & 1) << 16);
        QPHASE(cb, 0, 0, 0, 0, 2);
        QPHASE(cb, 0, 1, 0, 0, 0);
        QPHASE(cb, 1, 0, 0, 0, -1);
        QPHASE(cb, 1, 1, 0, 0, -1);
    }
}

// ---------------------------------------------------------------------------
// Fused QKV: C[8192,3072] = X . [Wq;Wk;Wv]^T, 256x256 tiles.
// Grid 384 = 8 XCD x 48; bm = wg/12 (256-row X tile), bn = wg%12
// (bn>>2 = matrix, (bn&3)*256 = channel base).
// ---------------------------------------------------------------------------
__global__ __launch_bounds__(512, 2) void qkv_gemm256(
    const u16* __restrict__ Xb,
    const u16* __restrict__ Wqb, const u16* __restrict__ Wkb, const u16* __restrict__ Wvb,
    u16* __restrict__ Qb, u16* __restrict__ Kb, u16* __restrict__ Vtb)
{
    __shared__ __attribute__((aligned(128))) char LDSRAW[131072];

    int id = blockIdx.x;
    int wg = (id & 7) * 48 + (id >> 3);      // bijective XCD swizzle (384 = 8*48)
    int bm = wg / 12, bn = wg % 12;
    int m0 = bm * 256;
    int nmat = bn >> 2;
    int chb  = (bn & 3) * 256;

    const u16* Wsel = (nmat == 0) ? Wqb : (nmat == 1) ? Wkb : Wvb;
    const u16* Arow = Xb   + (size_t)m0  * C_;
    const u16* Brow = Wsel + (size_t)chb * C_;

    f32x4 acc[8][4];
    const f32x4 z4 = {0.f, 0.f, 0.f, 0.f};
#pragma unroll
    for (int i = 0; i < 8; ++i)
#pragma unroll
        for (int j = 0; j < 4; ++j) acc[i][j] = z4;

    int tid = threadIdx.x, lane = tid & 63, w = tid >> 6;
    int quad = lane >> 4, l15 = lane & 15;
    int wm = w >> 2, wn = w & 3;

    if (nmat < 2) {
        qkv256_core<false>(Arow, Brow, LDSRAW, acc);
        // Q/K epilogue: D row = ch (quad*4+r), col = t (l15)
        u16* OUT = nmat ? Kb : Qb;
        float scale = nmat ? 1.0f : Q_SCALE;
#pragma unroll
        for (int mi = 0; mi < 8; ++mi) {
            size_t trow = (size_t)(m0 + (mi >> 2) * 128 + wm * 64 + (mi & 3) * 16 + l15) * C_;
#pragma unroll
            for (int nj = 0; nj < 4; ++nj) {
                int ch = chb + (nj >> 1) * 128 + wn * 32 + (nj & 1) * 16 + quad * 4;
                u16x4 v;
#pragma unroll
                for (int rr = 0; rr < 4; ++rr) v[rr] = f32_to_bf16(acc[mi][nj][rr] * scale);
                *(u16x4*)&OUT[trow + ch] = v;
            }
        }
    } else {
        qkv256_core<true>(Arow, Brow, LDSRAW, acc);
        // V epilogue: D row = t (quad*4+r), col = ch (l15) -> [B,H,D,T]
#pragma unroll
        for (int mi = 0; mi < 8; ++mi) {
            int t0 = m0 + (mi >> 2) * 128 + wm * 64 + (mi & 3) * 16 + quad * 4;
            int bb_ = t0 >> 11, tloc = t0 & (T_ - 1);
#pragma unroll
            for (int nj = 0; nj < 4; ++nj) {
                int ch = chb + (nj >> 1) * 128 + wn * 32 + (nj & 1) * 16 + l15;
                int h = ch >> 6, d = ch & 63;
                u16x4 v;
#pragma unroll
                for (int rr = 0; rr < 4; ++rr) v[rr] = f32_to_bf16(acc[mi][nj][rr]);
                *(u16x4*)&Vtb[(size_t)((bb_ * H_ + h) * D_ + d) * T_ + tloc] = v;
            }
        }
    }
}

// ---------------------------------------------------------------------------
// Pipelined GEMM core (counted-vmcnt, 2 phases per K-tile) — used by proj.
// ---------------------------------------------------------------------------
template<bool SWAP>
__device__ __forceinline__ void gemm8_core(const u16* __restrict__ Arow,
                                           const u16* __restrict__ Brow,
                                           char* lds, f32x4 (&acc)[4][4])
{
    int tid  = threadIdx.x;
    int lane = tid & 63, w = tid >> 6;
    int quad = lane >> 4, l15 = lane & 15;
    int wm = w >> 2, wn = w & 3;

    int r  = tid >> 2, s4 = tid & 3;
    int kg = ((s4 - (r >> 1)) & 3) * 8;
    const u16* xsrc  = Arow + (size_t)r * C_ + kg;
    const u16* wsrc0 = Brow + (size_t)r * C_ + kg;
    const u16* wsrc1 = Brow + (size_t)(128 + r) * C_ + kg;
    int wu = w << 10;

    int xoff[4], woff[4];
#pragma unroll
    for (int i = 0; i < 4; ++i) {
        int rx = wm * 64 + i * 16 + l15;
        xoff[i] = rx * 64 + (((rx >> 1) + quad) & 3) * 16;
        int rw = wn * 64 + i * 16 + l15;
        woff[i] = 16384 + rw * 64 + (((rw >> 1) + quad) & 3) * 16;
    }

    auto issue_group = [&](int g) {
        int db = (g >> 1) & 1, ks = g & 1;
        int koff = (g >> 1) * 64 + ks * 32;
        char* ldb = lds + db * 49152;
        async16(xsrc  + koff, ldb + ks * 8192 + wu);
        async16(wsrc0 + koff, ldb + 16384 + ks * 16384 + wu);
        async16(wsrc1 + koff, ldb + 16384 + ks * 16384 + 8192 + wu);
    };

    issue_group(0); issue_group(1); issue_group(2);
    asm volatile("s_waitcnt vmcnt(6)" ::: "memory");
    __builtin_amdgcn_s_barrier();
    asm volatile("" ::: "memory");

    for (int t = 0; t < NT_; ++t) {
        char* cb = lds + (t & 1) * 49152;
#pragma unroll
        for (int p = 0; p < 2; ++p) {
            bf16x8 xf[4], wf[4];
            const char* xb = cb + p * 8192;
            const char* wb = cb + p * 16384;
#pragma unroll
            for (int i = 0; i < 4; ++i) xf[i] = *(const bf16x8*)(xb + xoff[i]);
#pragma unroll
            for (int j = 0; j < 4; ++j) wf[j] = *(const bf16x8*)(wb + woff[j]);

            int g = 2 * t + 3 + p;
            if (g < 2 * NT_) issue_group(g);

            if (t < NT_ - 2) {
                asm volatile("s_waitcnt vmcnt(6)" ::: "memory");
            } else if (t == NT_ - 2) {
                if (p == 0) asm volatile("s_waitcnt vmcnt(6)" ::: "memory");
                else        asm volatile("s_waitcnt vmcnt(3)" ::: "memory");
            } else {
                if (p == 0) asm volatile("s_waitcnt vmcnt(0)" ::: "memory");
            }
            asm volatile("" ::: "memory");
            __builtin_amdgcn_s_barrier();
            asm volatile("" ::: "memory");

            __builtin_amdgcn_s_setprio(1);
#pragma unroll
            for (int i = 0; i < 4; ++i)
#pragma unroll
                for (int j = 0; j < 4; ++j) {
                    if (SWAP)
                        acc[i][j] = __builtin_amdgcn_mfma_f32_16x16x32_bf16(xf[i], wf[j], acc[i][j], 0, 0, 0);
                    else
                        acc[i][j] = __builtin_amdgcn_mfma_f32_16x16x32_bf16(wf[j], xf[i], acc[i][j], 0, 0, 0);
                }
            __builtin_amdgcn_s_setprio(0);
            asm volatile("" ::: "memory");
            __builtin_amdgcn_s_barrier();
            asm volatile("" ::: "memory");
        }
    }
}

// ---------------------------------------------------------------------------
// Flash attention (causal), S^T/O^T, max-free softmax, register-resident P.
// (unchanged from R11/R12)
// ---------------------------------------------------------------------------
__global__ __launch_bounds__(256, 4) void attn_kernel(
    const u16* __restrict__ Qb, const u16* __restrict__ Kb,
    const u16* __restrict__ Vtb, u16* __restrict__ Yb)
{
    __shared__ u16 SMA[16384];       // Ks0|Ks1|Vs0|Vs1 (4x8KB), reused by epilogue
    u16* Ks0 = SMA;
    u16* Ks1 = SMA + 4096;
    u16* Vs0 = SMA + 8192;
    u16* Vs1 = SMA + 12288;

    int id = blockIdx.x;
    int bh = id & 63;
    int jj = id >> 6;                // 0..15

    int tid = threadIdx.x, lane = tid & 63, w = tid >> 6;
    int quad = lane >> 4, l15 = lane & 15;
    int b = bh >> 4, h = bh & 15;

    int koff0[4], koff1[4], voff[4][4];
#pragma unroll
    for (int sblk = 0; sblk < 4; ++sblk) {
        int sr = sblk * 16 + l15;
        koff0[sblk] = (sr * 64 + ((quad + sr) & 7) * 8) * 2;
        koff1[sblk] = (sr * 64 + ((4 + quad + sr) & 7) * 8) * 2;
    }
#pragma unroll
    for (int n = 0; n < 4; ++n)
#pragma unroll
        for (int sblk = 0; sblk < 4; ++sblk) {
            int dr = n * 16 + l15;
            voff[n][sblk] = (dr * 64 + ((sblk * 2 + (quad >> 1) + dr) & 7) * 8 + (quad & 1) * 4) * 2;
        }

    int cA = tid, cB = tid + 256;
    int sA = cA >> 3, sB = cB >> 3;
    int offA = (((cA & 7) - sA) & 7) * 8;
    int offB = (((cB & 7) - sB) & 7) * 8;
    const u16* Kbase = Kb + (size_t)(b * T_) * C_ + h * 64;
    const u16* Vbase = Vtb + (size_t)bh * D_ * T_;
    int ldsb0 = (w * 64) * 16, ldsb1 = (256 + w * 64) * 16;

    const s16x4 ones = { (short)0x3F80, (short)0x3F80, (short)0x3F80, (short)0x3F80 };
    const f32x4 z4 = {0.f, 0.f, 0.f, 0.f};

    int qts[2] = { jj, 31 - jj };

    for (int pass = 0; pass < 2; ++pass) {
        int qt = qts[pass];
        int qbase = qt * 64;

        if (pass) __syncthreads();

        bf16x8 qf0, qf1;
        {
            const u16* q0 = Qb + ((size_t)(b * T_ + qbase + w * 16 + l15)) * C_ + h * 64;
            qf0 = *(const bf16x8*)(q0 + quad * 8);
            qf1 = *(const bf16x8*)(q0 + 32 + quad * 8);
        }

        f32x4 o_acc[4];
        f32x4 l_acc = z4;
#pragma unroll
        for (int n = 0; n < 4; ++n) o_acc[n] = z4;

        const int nst = qt + 1;

        const u16* kgpA = Kbase + (size_t)sA * C_ + offA;
        const u16* kgpB = Kbase + (size_t)sB * C_ + offB;
        const u16* vgpA = Vbase + sA * T_ + offA;
        const u16* vgpB = Vbase + sB * T_ + offB;

        async16(kgpA, (char*)Ks0 + ldsb0);
        async16(kgpB, (char*)Ks0 + ldsb1);
        async16(vgpA, (char*)Vs0 + ldsb0);
        async16(vgpB, (char*)Vs0 + ldsb1);
        kgpA += 64 * C_; kgpB += 64 * C_; vgpA += 64; vgpB += 64;

        auto tile_body = [&](int st, const u16* K_, const u16* V_, char* Kpf, char* Vpf) {
            __syncthreads();
            if (st + 1 < nst) {
                async16(kgpA, Kpf + ldsb0);
                async16(kgpB, Kpf + ldsb1);
                async16(vgpA, Vpf + ldsb0);
                async16(vgpB, Vpf + ldsb1);
            }
            kgpA += 64 * C_; kgpB += 64 * C_; vgpA += 64; vgpB += 64;

            f32x4 sv[4];
#pragma unroll
            for (int sblk = 0; sblk < 4; ++sblk) {
                bf16x8 k0 = *(const bf16x8*)((const char*)K_ + koff0[sblk]);
                bf16x8 k1 = *(const bf16x8*)((const char*)K_ + koff1[sblk]);
                f32x4 t0 = __builtin_amdgcn_mfma_f32_16x16x32_bf16(k0, qf0, z4, 0, 0, 0);
                sv[sblk] = __builtin_amdgcn_mfma_f32_16x16x32_bf16(k1, qf1, t0, 0, 0, 0);
            }

            if (st == qt) {
                int tl = w * 16 + l15;
#pragma unroll
                for (int sblk = 0; sblk < 4; ++sblk)
#pragma unroll
                    for (int r = 0; r < 4; ++r)
                        if (sblk * 16 + quad * 4 + r > tl) sv[sblk][r] = -1e30f;
            }

            s16x4 pfrag[4];
#pragma unroll
            for (int sblk = 0; sblk < 4; ++sblk) {
#pragma unroll
                for (int r = 0; r < 4; ++r)
                    sv[sblk][r] = __builtin_amdgcn_exp2f(sv[sblk][r]);
                uint2 pk;
                pk.x = pk_bf16(sv[sblk][0], sv[sblk][1]);
                pk.y = pk_bf16(sv[sblk][2], sv[sblk][3]);
                pfrag[sblk] = *(s16x4*)&pk;
                l_acc = __builtin_amdgcn_mfma_f32_16x16x16bf16_1k(ones, pfrag[sblk], l_acc, 0, 0, 0);
            }

#pragma unroll
            for (int n = 0; n < 4; ++n)
#pragma unroll
                for (int sblk = 0; sblk < 4; ++sblk) {
                    s16x4 va = *(const s16x4*)((const char*)V_ + voff[n][sblk]);
                    o_acc[n] = __builtin_amdgcn_mfma_f32_16x16x16bf16_1k(va, pfrag[sblk], o_acc[n], 0, 0, 0);
                }
        };

        for (int st = 0; st < nst; st += 2) {
            tile_body(st, Ks0, Vs0, (char*)Ks1, (char*)Vs1);
            if (st + 1 < nst)
                tile_body(st + 1, Ks1, Vs1, (char*)Ks0, (char*)Vs0);
        }

        __syncthreads();
        u16* PW = SMA + w * 1152;
        {
            float inv = 1.0f / l_acc[0];
#pragma unroll
            for (int n = 0; n < 4; ++n) {
                uint2 pk;
                pk.x = pk_bf16(o_acc[n][0] * inv, o_acc[n][1] * inv);
                pk.y = pk_bf16(o_acc[n][2] * inv, o_acc[n][3] * inv);
                *(u16x4*)&PW[l15 * 72 + n * 16 + quad * 4] = *(u16x4*)&pk;
            }
        }
        asm volatile("s_waitcnt lgkmcnt(0)" ::: "memory");
#pragma unroll
        for (int st = 0; st < 2; ++st) {
            int tr = st * 8 + (lane >> 3);
            int d8 = (lane & 7) * 8;
            u16x8 v = *(u16x8*)&PW[tr * 72 + d8];
            *(u16x8*)&Yb[(size_t)(b * T_ + qbase + w * 16 + tr) * C_ + h * 64 + d8] = v;
        }
    }
}

// ---------------------------------------------------------------------------
// Output projection on the 2-phase pipelined core (unchanged from R12).
// Grid 256 = 8 XCD x 32 = exactly one residency round.
// ---------------------------------------------------------------------------
__global__ __launch_bounds__(512, 2) void proj_gemm8(
    const u16* __restrict__ Yb, const u16* __restrict__ Wob,
    const float* __restrict__ bo, float* __restrict__ out)
{
    __shared__ __attribute__((aligned(128))) char LDSRAW[98304];

    int id = blockIdx.x;
    int wg = (id & 7) * 32 + (id >> 3);
    int bm = wg >> 2, bn = wg & 3;
    int m0 = bm * 128, n0 = bn * 256;

    f32x4 acc[4][4];
    const f32x4 z4 = {0.f, 0.f, 0.f, 0.f};
#pragma unroll
    for (int i = 0; i < 4; ++i)
#pragma unroll
        for (int j = 0; j < 4; ++j) acc[i][j] = z4;

    gemm8_core<false>(Yb + (size_t)m0 * C_, Wob + (size_t)n0 * C_, LDSRAW, acc);

    int tid = threadIdx.x, lane = tid & 63, w = tid >> 6;
    int quad = lane >> 4, l15 = lane & 15;
    int wm = w >> 2, wn = w & 3;

#pragma unroll
    for (int j = 0; j < 4; ++j) {
        int ch = n0 + wn * 64 + j * 16 + quad * 4;
        f32x4 bv = *(const f32x4*)&bo[ch];
#pragma unroll
        for (int i = 0; i < 4; ++i) {
            int t = m0 + wm * 64 + i * 16 + l15;
            f32x4 v = acc[i][j] + bv;
            *(f32x4*)&out[(size_t)t * C_ + ch] = v;
        }
    }
}

// ---------------------------------------------------------------------------
// launch
// ---------------------------------------------------------------------------
extern "C" void kernel_launch(void* const* d_in, const int* in_sizes, int n_in,
                              void* d_out, int out_size, void* d_ws, size_t ws_size,
                              hipStream_t stream) {
    const float* X  = (const float*)d_in[0];
    const float* Wq = (const float*)d_in[1];
    const float* Wk = (const float*)d_in[2];
    const float* Wv = (const float*)d_in[3];
    const float* Wo = (const float*)d_in[4];
    const float* bo = (const float*)d_in[5];

    char* ws = (char*)d_ws;
    u16* Xb  = (u16*)(ws);                       // 16 MB  [BT, C] bf16
    u16* Wqb = (u16*)(ws + (16u << 20));         //  2 MB
    u16* Wkb = (u16*)(ws + (18u << 20));         //  2 MB
    u16* Wvb = (u16*)(ws + (20u << 20));         //  2 MB
    u16* Wob = (u16*)(ws + (22u << 20));         //  2 MB
    u16* Qb  = (u16*)(ws + (24u << 20));         // 16 MB  [BT, C] (pre-scaled)
    u16* Kb  = (u16*)(ws + (40u << 20));         // 16 MB  [BT, C]
    u16* Vtb = (u16*)(ws + (56u << 20));         // 16 MB  [B,H,D,T]
    u16* Yb  = (u16*)(ws + (72u << 20));         // 16 MB  [BT, C]

    cast_all_kernel<<<dim3(8192 + 4 * 1024), 256, 0, stream>>>(
        X, Wq, Wk, Wv, Wo, Xb, Wqb, Wkb, Wvb, Wob);

    qkv_gemm256<<<dim3(384), 512, 0, stream>>>(Xb, Wqb, Wkb, Wvb, Qb, Kb, Vtb);
    attn_kernel<<<dim3(1024), 256, 0, stream>>>(Qb, Kb, Vtb, Yb);
    proj_gemm8<<<dim3(256), 512, 0, stream>>>(Yb, Wob, bo, (float*)d_out);
}

// Round 3
// 228.440 us; speedup vs baseline: 1.1232x; 1.0559x over previous
//
#include <hip/hip_runtime.h>
#include <hip/hip_bf16.h>
#include <stdint.h>

// ---------------------------------------------------------------------------
// SplitCausalSelfAttention on MI355X (gfx950), bf16 MFMA implementation.
// B=4, T=2048, C=1024, H=16, D=64.
// R14: qkv rebuilt as 128x384-tile pipelined GEMM, grid 512 = 64bm x 8bn =
//      EXACTLY 2 residency rounds (R13's 384-block grid wasted 25-33% in a
//      half-empty round).  3 phases/K-tile (16 MFMA each), 4 LDS units
//      {A,B0,B1,B2} (16KB) x 2 dbuf = 128KB; ONE vmcnt(6) gate per K-tile
//      (m201 discipline, was 3 gates) with ledger-verified issue stream
//      t.p0->(t+1).u3, t.p1->(t+2).u0,u1, t.p2->(t+2).u2.  bn = XCD so each
//      XCD's 64 blocks share one 768KB W panel (L2-resident).  W read as
//      contiguous [3072,1024] concat (Wq/Wk/Wv adjacent in ws).  Epilogue
//      dispatches per 16-col frag: Q(scaled)/K direct, V via swapped-operand
//      blocks (bn6,7) or scalar t-run stores (bn5 boundary block).
//      attn/proj/cast unchanged.
// ---------------------------------------------------------------------------

typedef unsigned short u16;
typedef __attribute__((ext_vector_type(8))) __bf16 bf16x8;  // 4 VGPRs (A/B frag, K=32)
typedef __attribute__((ext_vector_type(4))) float  f32x4;   // C/D frag
typedef __attribute__((ext_vector_type(4))) unsigned short u16x4;
typedef __attribute__((ext_vector_type(8))) unsigned short u16x8;
typedef __attribute__((ext_vector_type(4))) short s16x4;    // 2 VGPRs (A/B frag, K=16)

#define B_  4
#define T_  2048
#define C_  1024
#define H_  16
#define D_  64
#define BT_ (B_ * T_)
#define NT_ 16        // K-tiles of 64 over K=1024

// scale = 1/sqrt(D) folded with log2(e) so softmax uses exp2
#define Q_SCALE 0.1803368801111204f

__device__ __forceinline__ u16 f32_to_bf16(float f) {
    unsigned int u = __float_as_uint(f);
    unsigned int r = (u + 0x7FFFu + ((u >> 16) & 1u)) >> 16;
    return (u16)r;
}

__device__ __forceinline__ unsigned int pk_bf16(float a, float b) {
    float2 f2; f2.x = a; f2.y = b;
    __hip_bfloat162 h = __float22bfloat162_rn(f2);
    return *(unsigned int*)&h;
}

__device__ __forceinline__ void async16(const void* g, void* lds) {
    __builtin_amdgcn_global_load_lds(
        (const __attribute__((address_space(1))) void*)g,
        (__attribute__((address_space(3))) void*)lds, 16, 0, 0);
}

// ---------------------------------------------------------------------------
// single cast kernel: X (8192 blocks) + 4 weights (1024 blocks each)
// ---------------------------------------------------------------------------
__global__ void cast_all_kernel(const float* __restrict__ X,
                                const float* __restrict__ w0, const float* __restrict__ w1,
                                const float* __restrict__ w2, const float* __restrict__ w3,
                                u16* __restrict__ xo,
                                u16* __restrict__ o0, u16* __restrict__ o1,
                                u16* __restrict__ o2, u16* __restrict__ o3) {
    int id = blockIdx.x;
    const float* in; u16* out; int i;
    if (id < 8192) {
        in = X; out = xo; i = id * 256 + threadIdx.x;
    } else {
        int k = (id - 8192) >> 10;
        in  = (k == 0) ? w0 : (k == 1) ? w1 : (k == 2) ? w2 : w3;
        out = (k == 0) ? o0 : (k == 1) ? o1 : (k == 2) ? o2 : o3;
        i = ((id - 8192) & 1023) * 256 + threadIdx.x;
    }
    float4 v = ((const float4*)in)[i];
    u16x4 o;
    o[0] = f32_to_bf16(v.x); o[1] = f32_to_bf16(v.y);
    o[2] = f32_to_bf16(v.z); o[3] = f32_to_bf16(v.w);
    ((u16x4*)out)[i] = o;
}

// ---------------------------------------------------------------------------
// qkv 128x384 3-phase core.
// LDS: dbuf d at d*65536; unit u at u*16384: u0 = A (X) rows 0-127,
// u1/u2/u3 = B (Wcat) rows 0-127 / 128-255 / 256-383.  Within a unit:
// row r (0..127) at r*128B, 8 slots of 16B; slot s holds k-group (s-r)&7
// (k-rotation swizzle, measured conflict-free; pre-swizzled global src).
// Waves 2m x 4n: wave tile 64 x 96.  xf: rows wm*64+mi*16+l15 (unit 0,
// read once per K-tile at p0, reg-reused).  wf frag nj (0..5): unit
// 1+(nj>>1), row wn*32+(nj&1)*16+l15.  Phase p reads wf nj={2p,2p+1}:
// p0 -> units {0,1}, p1 -> {2}, p2 -> {3}.  16 MFMA per phase.
// Issue stream: t.p0 -> (t+1).u3; t.p1 -> (t+2).u0,u1; t.p2 -> (t+2).u2.
// Single gate vmcnt(6) at t.p2 covers ALL of tile t+1 (youngest t+1 unit
// = u3 @ t.p0; younger: 6 loads).  Tail: t=14 gate vmcnt(0); t=15 none.
// WAR: every issue targets a slot whose last reader is >=1 barrier-pair
// earlier (u3 other-dbuf read (t-1).p2; u0/u1 read t.p0, issued t.p1;
// u2 read t.p1, issued t.p2).
// ---------------------------------------------------------------------------
#define PH384(CB, P, ISSUE, GATE)                                              \
  {                                                                            \
    if ((P) == 0) {                                                            \
      _Pragma("unroll") for (int mi = 0; mi < 4; ++mi)                         \
        _Pragma("unroll") for (int ks = 0; ks < 2; ++ks)                       \
          xf[mi][ks] = *(const bf16x8*)((CB) + axoff[mi][ks]);                 \
    }                                                                          \
    _Pragma("unroll") for (int e = 0; e < 2; ++e)                              \
      _Pragma("unroll") for (int ks = 0; ks < 2; ++ks)                         \
        wf[e][ks] = *(const bf16x8*)((CB) + bwoff[2 * (P) + e][ks]);           \
    ISSUE;                                                                     \
    if ((P) == 0) asm volatile("s_waitcnt lgkmcnt(8)" ::: "memory");           \
    if ((GATE) == 6) asm volatile("s_waitcnt vmcnt(6)" ::: "memory");          \
    else if ((GATE) == 0) asm volatile("s_waitcnt vmcnt(0)" ::: "memory");     \
    __builtin_amdgcn_s_barrier();                                              \
    asm volatile("" ::: "memory");                                             \
    __builtin_amdgcn_s_setprio(1);                                             \
    _Pragma("unroll") for (int mi = 0; mi < 4; ++mi)                           \
      _Pragma("unroll") for (int e = 0; e < 2; ++e) {                          \
        f32x4 a_ = acc[mi][2 * (P) + e];                                       \
        if (SWAPV) {                                                           \
          a_ = __builtin_amdgcn_mfma_f32_16x16x32_bf16(xf[mi][0], wf[e][0], a_, 0, 0, 0); \
          a_ = __builtin_amdgcn_mfma_f32_16x16x32_bf16(xf[mi][1], wf[e][1], a_, 0, 0, 0); \
        } else {                                                               \
          a_ = __builtin_amdgcn_mfma_f32_16x16x32_bf16(wf[e][0], xf[mi][0], a_, 0, 0, 0); \
          a_ = __builtin_amdgcn_mfma_f32_16x16x32_bf16(wf[e][1], xf[mi][1], a_, 0, 0, 0); \
        }                                                                      \
        acc[mi][2 * (P) + e] = a_;                                             \
      }                                                                        \
    __builtin_amdgcn_s_setprio(0);                                             \
    asm volatile("" ::: "memory");                                             \
    __builtin_amdgcn_s_barrier();                                              \
    asm volatile("" ::: "memory");                                             \
  }

template<bool SWAPV>
__device__ __forceinline__ void qkv384_core(const u16* __restrict__ Arow,
                                            const u16* __restrict__ Brow,
                                            char* lds, f32x4 (&acc)[4][6])
{
    int tid = threadIdx.x, lane = tid & 63, w = tid >> 6;
    int quad = lane >> 4, l15 = lane & 15;
    int wm = w >> 2, wn = w & 3;

    // staging: 2 async16/thread/unit; pre-swizzled global k-group
    int gc = (((tid & 7) - (tid >> 3)) & 7) * 8;
    const u16* asrc = Arow + (size_t)(tid >> 3) * C_ + gc;
    const u16* bsrc = Brow + (size_t)(tid >> 3) * C_ + gc;

    auto issue_unit = [&](int kt, int u) {
        char* d = lds + ((kt & 1) << 16) + (u << 14) + (w << 10);
        int ko = kt * 64;
        const u16* s = (u == 0) ? (asrc + ko)
                                : (bsrc + (size_t)(u - 1) * 128 * C_ + ko);
        async16(s, d);
        async16(s + (size_t)64 * C_, d + 8192);
    };

    // loop-invariant LDS read byte offsets
    int axoff[4][2], bwoff[6][2];
#pragma unroll
    for (int mi = 0; mi < 4; ++mi) {
        int r = wm * 64 + mi * 16 + l15;
#pragma unroll
        for (int ks = 0; ks < 2; ++ks)
            axoff[mi][ks] = r * 128 + (((ks * 4 + quad + r) & 7) << 4);
    }
#pragma unroll
    for (int nj = 0; nj < 6; ++nj) {
        int r = wn * 32 + (nj & 1) * 16 + l15;
#pragma unroll
        for (int ks = 0; ks < 2; ++ks)
            bwoff[nj][ks] = (1 + (nj >> 1)) * 16384 + r * 128 + (((ks * 4 + quad + r) & 7) << 4);
    }

    bf16x8 xf[4][2];   // A-frags, read once per K-tile, reused p1/p2
    bf16x8 wf[2][2];   // B-frags for current phase

    // prologue: t0 all units + t1.{u0,u1,u2}; gate t0 (6 younger = t1's)
    issue_unit(0, 0); issue_unit(0, 1); issue_unit(0, 2); issue_unit(0, 3);
    issue_unit(1, 0); issue_unit(1, 1); issue_unit(1, 2);
    asm volatile("s_waitcnt vmcnt(6)" ::: "memory");
    __builtin_amdgcn_s_barrier();
    asm volatile("" ::: "memory");

    for (int t = 0; t < NT_; ++t) {
        char* cb = lds + ((t & 1) << 16);
        PH384(cb, 0, { if (t + 1 < NT_) issue_unit(t + 1, 3); }, -1);
        PH384(cb, 1, { if (t + 2 < NT_) { issue_unit(t + 2, 0); issue_unit(t + 2, 1); } }, -1);
        int gate = (t < NT_ - 2) ? 6 : ((t == NT_ - 2) ? 0 : -1);
        PH384(cb, 2, { if (t + 2 < NT_) issue_unit(t + 2, 2); }, gate);
    }
}

// ---------------------------------------------------------------------------
// Fused QKV: C[8192,3072] = X . Wcat^T, 128x384 tiles, grid 512 (2 exact
// rounds).  wg = (id&7)*64 + (id>>3); bn = wg>>6 (= XCD, W panel L2-pinned),
// bm = wg&63.  Wcat = contiguous [3072,1024] (Wq|Wk|Wv adjacent in ws).
// ---------------------------------------------------------------------------
__global__ __launch_bounds__(512, 2) void qkv_gemm384(
    const u16* __restrict__ Xb, const u16* __restrict__ Wcat,
    u16* __restrict__ Qb, u16* __restrict__ Kb, u16* __restrict__ Vtb)
{
    __shared__ __attribute__((aligned(128))) char LDSRAW[131072];

    int id = blockIdx.x;
    int wg = (id & 7) * 64 + (id >> 3);      // bijective XCD swizzle (512=8*64)
    int bn = wg >> 6;                        // 0..7 (uniform per XCD)
    int bm = wg & 63;                        // 0..63
    int m0 = bm * 128;
    int chb = bn * 384;

    const u16* Arow = Xb   + (size_t)m0  * C_;
    const u16* Brow = Wcat + (size_t)chb * C_;

    f32x4 acc[4][6];
    const f32x4 z4 = {0.f, 0.f, 0.f, 0.f};
#pragma unroll
    for (int i = 0; i < 4; ++i)
#pragma unroll
        for (int j = 0; j < 6; ++j) acc[i][j] = z4;

    int tid = threadIdx.x, lane = tid & 63, w = tid >> 6;
    int quad = lane >> 4, l15 = lane & 15;
    int wm = w >> 2, wn = w & 3;

    if (bn < 6) {
        // Q/K (and bn5's V spill-over).  D row = ch (quad*4+rr), col = t (l15).
        qkv384_core<false>(Arow, Brow, LDSRAW, acc);
#pragma unroll
        for (int mi = 0; mi < 4; ++mi) {
            int tg = m0 + wm * 64 + mi * 16 + l15;
#pragma unroll
            for (int nj = 0; nj < 6; ++nj) {
                int colb = chb + (nj >> 1) * 128 + wn * 32 + (nj & 1) * 16 + quad * 4;
                if (colb < 2048) {
                    u16* OUT = (colb < 1024) ? Qb : Kb;
                    float sc = (colb < 1024) ? Q_SCALE : 1.0f;
                    u16x4 v;
#pragma unroll
                    for (int rr = 0; rr < 4; ++rr) v[rr] = f32_to_bf16(acc[mi][nj][rr] * sc);
                    *(u16x4*)&OUT[(size_t)tg * C_ + (colb & 1023)] = v;
                } else {
                    // V frags of the K|V boundary block: scalar stores,
                    // 16-lane t-runs (32B coalesced groups) along T.
                    int b_ = tg >> 11, tl = tg & (T_ - 1);
#pragma unroll
                    for (int rr = 0; rr < 4; ++rr) {
                        int ch = colb + rr;
                        int h = (ch >> 6) & 15, d = ch & 63;
                        Vtb[((size_t)(b_ * H_ + h) * D_ + d) * T_ + tl] =
                            f32_to_bf16(acc[mi][nj][rr]);
                    }
                }
            }
        }
    } else {
        // pure-V blocks: swapped operands.  D row = t (quad*4+rr), col = ch (l15).
        qkv384_core<true>(Arow, Brow, LDSRAW, acc);
#pragma unroll
        for (int mi = 0; mi < 4; ++mi) {
            int t0 = m0 + wm * 64 + mi * 16 + quad * 4;
            int b_ = t0 >> 11, tl = t0 & (T_ - 1);
#pragma unroll
            for (int nj = 0; nj < 6; ++nj) {
                int ch = chb + (nj >> 1) * 128 + wn * 32 + (nj & 1) * 16 + l15;
                int h = (ch >> 6) & 15, d = ch & 63;
                u16x4 v;
#pragma unroll
                for (int rr = 0; rr < 4; ++rr) v[rr] = f32_to_bf16(acc[mi][nj][rr]);
                *(u16x4*)&Vtb[((size_t)(b_ * H_ + h) * D_ + d) * T_ + tl] = v;
            }
        }
    }
}

// ---------------------------------------------------------------------------
// Pipelined GEMM core (counted-vmcnt, 2 phases per K-tile) — used by proj.
// ---------------------------------------------------------------------------
template<bool SWAP>
__device__ __forceinline__ void gemm8_core(const u16* __restrict__ Arow,
                                           const u16* __restrict__ Brow,
                                           char* lds, f32x4 (&acc)[4][4])
{
    int tid  = threadIdx.x;
    int lane = tid & 63, w = tid >> 6;
    int quad = lane >> 4, l15 = lane & 15;
    int wm = w >> 2, wn = w & 3;

    int r  = tid >> 2, s4 = tid & 3;
    int kg = ((s4 - (r >> 1)) & 3) * 8;
    const u16* xsrc  = Arow + (size_t)r * C_ + kg;
    const u16* wsrc0 = Brow + (size_t)r * C_ + kg;
    const u16* wsrc1 = Brow + (size_t)(128 + r) * C_ + kg;
    int wu = w << 10;

    int xoff[4], woff[4];
#pragma unroll
    for (int i = 0; i < 4; ++i) {
        int rx = wm * 64 + i * 16 + l15;
        xoff[i] = rx * 64 + (((rx >> 1) + quad) & 3) * 16;
        int rw = wn * 64 + i * 16 + l15;
        woff[i] = 16384 + rw * 64 + (((rw >> 1) + quad) & 3) * 16;
    }

    auto issue_group = [&](int g) {
        int db = (g >> 1) & 1, ks = g & 1;
        int koff = (g >> 1) * 64 + ks * 32;
        char* ldb = lds + db * 49152;
        async16(xsrc  + koff, ldb + ks * 8192 + wu);
        async16(wsrc0 + koff, ldb + 16384 + ks * 16384 + wu);
        async16(wsrc1 + koff, ldb + 16384 + ks * 16384 + 8192 + wu);
    };

    issue_group(0); issue_group(1); issue_group(2);
    asm volatile("s_waitcnt vmcnt(6)" ::: "memory");
    __builtin_amdgcn_s_barrier();
    asm volatile("" ::: "memory");

    for (int t = 0; t < NT_; ++t) {
        char* cb = lds + (t & 1) * 49152;
#pragma unroll
        for (int p = 0; p < 2; ++p) {
            bf16x8 xf[4], wf[4];
            const char* xb = cb + p * 8192;
            const char* wb = cb + p * 16384;
#pragma unroll
            for (int i = 0; i < 4; ++i) xf[i] = *(const bf16x8*)(xb + xoff[i]);
#pragma unroll
            for (int j = 0; j < 4; ++j) wf[j] = *(const bf16x8*)(wb + woff[j]);

            int g = 2 * t + 3 + p;
            if (g < 2 * NT_) issue_group(g);

            if (t < NT_ - 2) {
                asm volatile("s_waitcnt vmcnt(6)" ::: "memory");
            } else if (t == NT_ - 2) {
                if (p == 0) asm volatile("s_waitcnt vmcnt(6)" ::: "memory");
                else        asm volatile("s_waitcnt vmcnt(3)" ::: "memory");
            } else {
                if (p == 0) asm volatile("s_waitcnt vmcnt(0)" ::: "memory");
            }
            asm volatile("" ::: "memory");
            __builtin_amdgcn_s_barrier();
            asm volatile("" ::: "memory");

            __builtin_amdgcn_s_setprio(1);
#pragma unroll
            for (int i = 0; i < 4; ++i)
#pragma unroll
                for (int j = 0; j < 4; ++j) {
                    if (SWAP)
                        acc[i][j] = __builtin_amdgcn_mfma_f32_16x16x32_bf16(xf[i], wf[j], acc[i][j], 0, 0, 0);
                    else
                        acc[i][j] = __builtin_amdgcn_mfma_f32_16x16x32_bf16(wf[j], xf[i], acc[i][j], 0, 0, 0);
                }
            __builtin_amdgcn_s_setprio(0);
            asm volatile("" ::: "memory");
            __builtin_amdgcn_s_barrier();
            asm volatile("" ::: "memory");
        }
    }
}

// ---------------------------------------------------------------------------
// Flash attention (causal), S^T/O^T, max-free softmax, register-resident P.
// (unchanged from R11/R12/R13)
// ---------------------------------------------------------------------------
__global__ __launch_bounds__(256, 4) void attn_kernel(
    const u16* __restrict__ Qb, const u16* __restrict__ Kb,
    const u16* __restrict__ Vtb, u16* __restrict__ Yb)
{
    __shared__ u16 SMA[16384];       // Ks0|Ks1|Vs0|Vs1 (4x8KB), reused by epilogue
    u16* Ks0 = SMA;
    u16* Ks1 = SMA + 4096;
    u16* Vs0 = SMA + 8192;
    u16* Vs1 = SMA + 12288;

    int id = blockIdx.x;
    int bh = id & 63;
    int jj = id >> 6;                // 0..15

    int tid = threadIdx.x, lane = tid & 63, w = tid >> 6;
    int quad = lane >> 4, l15 = lane & 15;
    int b = bh >> 4, h = bh & 15;

    int koff0[4], koff1[4], voff[4][4];
#pragma unroll
    for (int sblk = 0; sblk < 4; ++sblk) {
        int sr = sblk * 16 + l15;
        koff0[sblk] = (sr * 64 + ((quad + sr) & 7) * 8) * 2;
        koff1[sblk] = (sr * 64 + ((4 + quad + sr) & 7) * 8) * 2;
    }
#pragma unroll
    for (int n = 0; n < 4; ++n)
#pragma unroll
        for (int sblk = 0; sblk < 4; ++sblk) {
            int dr = n * 16 + l15;
            voff[n][sblk] = (dr * 64 + ((sblk * 2 + (quad >> 1) + dr) & 7) * 8 + (quad & 1) * 4) * 2;
        }

    int cA = tid, cB = tid + 256;
    int sA = cA >> 3, sB = cB >> 3;
    int offA = (((cA & 7) - sA) & 7) * 8;
    int offB = (((cB & 7) - sB) & 7) * 8;
    const u16* Kbase = Kb + (size_t)(b * T_) * C_ + h * 64;
    const u16* Vbase = Vtb + (size_t)bh * D_ * T_;
    int ldsb0 = (w * 64) * 16, ldsb1 = (256 + w * 64) * 16;

    const s16x4 ones = { (short)0x3F80, (short)0x3F80, (short)0x3F80, (short)0x3F80 };
    const f32x4 z4 = {0.f, 0.f, 0.f, 0.f};

    int qts[2] = { jj, 31 - jj };

    for (int pass = 0; pass < 2; ++pass) {
        int qt = qts[pass];
        int qbase = qt * 64;

        if (pass) __syncthreads();

        bf16x8 qf0, qf1;
        {
            const u16* q0 = Qb + ((size_t)(b * T_ + qbase + w * 16 + l15)) * C_ + h * 64;
            qf0 = *(const bf16x8*)(q0 + quad * 8);
            qf1 = *(const bf16x8*)(q0 + 32 + quad * 8);
        }

        f32x4 o_acc[4];
        f32x4 l_acc = z4;
#pragma unroll
        for (int n = 0; n < 4; ++n) o_acc[n] = z4;

        const int nst = qt + 1;

        const u16* kgpA = Kbase + (size_t)sA * C_ + offA;
        const u16* kgpB = Kbase + (size_t)sB * C_ + offB;
        const u16* vgpA = Vbase + sA * T_ + offA;
        const u16* vgpB = Vbase + sB * T_ + offB;

        async16(kgpA, (char*)Ks0 + ldsb0);
        async16(kgpB, (char*)Ks0 + ldsb1);
        async16(vgpA, (char*)Vs0 + ldsb0);
        async16(vgpB, (char*)Vs0 + ldsb1);
        kgpA += 64 * C_; kgpB += 64 * C_; vgpA += 64; vgpB += 64;

        auto tile_body = [&](int st, const u16* K_, const u16* V_, char* Kpf, char* Vpf) {
            __syncthreads();
            if (st + 1 < nst) {
                async16(kgpA, Kpf + ldsb0);
                async16(kgpB, Kpf + ldsb1);
                async16(vgpA, Vpf + ldsb0);
                async16(vgpB, Vpf + ldsb1);
            }
            kgpA += 64 * C_; kgpB += 64 * C_; vgpA += 64; vgpB += 64;

            f32x4 sv[4];
#pragma unroll
            for (int sblk = 0; sblk < 4; ++sblk) {
                bf16x8 k0 = *(const bf16x8*)((const char*)K_ + koff0[sblk]);
                bf16x8 k1 = *(const bf16x8*)((const char*)K_ + koff1[sblk]);
                f32x4 t0 = __builtin_amdgcn_mfma_f32_16x16x32_bf16(k0, qf0, z4, 0, 0, 0);
                sv[sblk] = __builtin_amdgcn_mfma_f32_16x16x32_bf16(k1, qf1, t0, 0, 0, 0);
            }

            if (st == qt) {
                int tl = w * 16 + l15;
#pragma unroll
                for (int sblk = 0; sblk < 4; ++sblk)
#pragma unroll
                    for (int r = 0; r < 4; ++r)
                        if (sblk * 16 + quad * 4 + r > tl) sv[sblk][r] = -1e30f;
            }

            s16x4 pfrag[4];
#pragma unroll
            for (int sblk = 0; sblk < 4; ++sblk) {
#pragma unroll
                for (int r = 0; r < 4; ++r)
                    sv[sblk][r] = __builtin_amdgcn_exp2f(sv[sblk][r]);
                uint2 pk;
                pk.x = pk_bf16(sv[sblk][0], sv[sblk][1]);
                pk.y = pk_bf16(sv[sblk][2], sv[sblk][3]);
                pfrag[sblk] = *(s16x4*)&pk;
                l_acc = __builtin_amdgcn_mfma_f32_16x16x16bf16_1k(ones, pfrag[sblk], l_acc, 0, 0, 0);
            }

#pragma unroll
            for (int n = 0; n < 4; ++n)
#pragma unroll
                for (int sblk = 0; sblk < 4; ++sblk) {
                    s16x4 va = *(const s16x4*)((const char*)V_ + voff[n][sblk]);
                    o_acc[n] = __builtin_amdgcn_mfma_f32_16x16x16bf16_1k(va, pfrag[sblk], o_acc[n], 0, 0, 0);
                }
        };

        for (int st = 0; st < nst; st += 2) {
            tile_body(st, Ks0, Vs0, (char*)Ks1, (char*)Vs1);
            if (st + 1 < nst)
                tile_body(st + 1, Ks1, Vs1, (char*)Ks0, (char*)Vs0);
        }

        __syncthreads();
        u16* PW = SMA + w * 1152;
        {
            float inv = 1.0f / l_acc[0];
#pragma unroll
            for (int n = 0; n < 4; ++n) {
                uint2 pk;
                pk.x = pk_bf16(o_acc[n][0] * inv, o_acc[n][1] * inv);
                pk.y = pk_bf16(o_acc[n][2] * inv, o_acc[n][3] * inv);
                *(u16x4*)&PW[l15 * 72 + n * 16 + quad * 4] = *(u16x4*)&pk;
            }
        }
        asm volatile("s_waitcnt lgkmcnt(0)" ::: "memory");
#pragma unroll
        for (int st = 0; st < 2; ++st) {
            int tr = st * 8 + (lane >> 3);
            int d8 = (lane & 7) * 8;
            u16x8 v = *(u16x8*)&PW[tr * 72 + d8];
            *(u16x8*)&Yb[(size_t)(b * T_ + qbase + w * 16 + tr) * C_ + h * 64 + d8] = v;
        }
    }
}

// ---------------------------------------------------------------------------
// Output projection on the 2-phase pipelined core (unchanged).
// Grid 256 = 8 XCD x 32 = exactly one residency round.
// ---------------------------------------------------------------------------
__global__ __launch_bounds__(512, 2) void proj_gemm8(
    const u16* __restrict__ Yb, const u16* __restrict__ Wob,
    const float* __restrict__ bo, float* __restrict__ out)
{
    __shared__ __attribute__((aligned(128))) char LDSRAW[98304];

    int id = blockIdx.x;
    int wg = (id & 7) * 32 + (id >> 3);
    int bm = wg >> 2, bn = wg & 3;
    int m0 = bm * 128, n0 = bn * 256;

    f32x4 acc[4][4];
    const f32x4 z4 = {0.f, 0.f, 0.f, 0.f};
#pragma unroll
    for (int i = 0; i < 4; ++i)
#pragma unroll
        for (int j = 0; j < 4; ++j) acc[i][j] = z4;

    gemm8_core<false>(Yb + (size_t)m0 * C_, Wob + (size_t)n0 * C_, LDSRAW, acc);

    int tid = threadIdx.x, lane = tid & 63, w = tid >> 6;
    int quad = lane >> 4, l15 = lane & 15;
    int wm = w >> 2, wn = w & 3;

#pragma unroll
    for (int j = 0; j < 4; ++j) {
        int ch = n0 + wn * 64 + j * 16 + quad * 4;
        f32x4 bv = *(const f32x4*)&bo[ch];
#pragma unroll
        for (int i = 0; i < 4; ++i) {
            int t = m0 + wm * 64 + i * 16 + l15;
            f32x4 v = acc[i][j] + bv;
            *(f32x4*)&out[(size_t)t * C_ + ch] = v;
        }
    }
}

// ---------------------------------------------------------------------------
// launch
// ---------------------------------------------------------------------------
extern "C" void kernel_launch(void* const* d_in, const int* in_sizes, int n_in,
                              void* d_out, int out_size, void* d_ws, size_t ws_size,
                              hipStream_t stream) {
    const float* X  = (const float*)d_in[0];
    const float* Wq = (const float*)d_in[1];
    const float* Wk = (const float*)d_in[2];
    const float* Wv = (const float*)d_in[3];
    const float* Wo = (const float*)d_in[4];
    const float* bo = (const float*)d_in[5];

    char* ws = (char*)d_ws;
    u16* Xb  = (u16*)(ws);                       // 16 MB  [BT, C] bf16
    u16* Wqb = (u16*)(ws + (16u << 20));         //  2 MB  } contiguous
    u16* Wkb = (u16*)(ws + (18u << 20));         //  2 MB  } [3072,1024]
    u16* Wvb = (u16*)(ws + (20u << 20));         //  2 MB  } Wcat
    u16* Wob = (u16*)(ws + (22u << 20));         //  2 MB
    u16* Qb  = (u16*)(ws + (24u << 20));         // 16 MB  [BT, C] (pre-scaled)
    u16* Kb  = (u16*)(ws + (40u << 20));         // 16 MB  [BT, C]
    u16* Vtb = (u16*)(ws + (56u << 20));         // 16 MB  [B,H,D,T]
    u16* Yb  = (u16*)(ws + (72u << 20));         // 16 MB  [BT, C]

    cast_all_kernel<<<dim3(8192 + 4 * 1024), 256, 0, stream>>>(
        X, Wq, Wk, Wv, Wo, Xb, Wqb, Wkb, Wvb, Wob);

    qkv_gemm384<<<dim3(512), 512, 0, stream>>>(Xb, Wqb, Qb, Kb, Vtb);
    attn_kernel<<<dim3(1024), 256, 0, stream>>>(Qb, Kb, Vtb, Yb);
    proj_gemm8<<<dim3(256), 512, 0, stream>>>(Yb, Wob, bo, (float*)d_out);
}